// Round 1
// baseline (375.815 us; speedup 1.0000x reference)
//
#include <hip/hip_runtime.h>
#include <hip/hip_bf16.h>

// ROUND 17 (resubmit — previous bench died to container infra, no counters).
// r16 = 370 us. agg_csr proven fill-BW-bound (r15==r16 at 65.7 us,
// 87.8 MB L2-miss @ ~1.56 TB/s regardless of gather count/ILP). Changes:
//  1) non-temporal loads (q, s) + nt stores (layer-2 out) in agg: stop
//     polluting per-XCD L2 with once-touched streams; L2 keeps more of the
//     12.8 MB kv gather set -> fewer misses. hb (layer-1 out) stays cached
//     (gemm2 re-reads it).
//  2) scatter_src fused into gemm1 dispatch (blocks >=782) - independent
//     work, hides ~20 us of serial scatter under the MFMA gemm.
//  3) agg unroll 16 (covers avg degree in one batch).

#define N_NODES 50000
#define N_EDGES 800000
#define NB_SCAN 196   // ceil(50000/256)
#define NPAD    50048 // 782*64
#define GEMM_BLKS 782
#define SCAT_BLKS 3125

using bf16 = __hip_bfloat16;
typedef __attribute__((ext_vector_type(8))) short bf16x8;
typedef __attribute__((ext_vector_type(4))) float f32x4;

__device__ __forceinline__ float b2f(unsigned short u) {
    unsigned int x = ((unsigned int)u) << 16;
    return __builtin_bit_cast(float, x);
}

struct WPtrs { const float* p[8]; };

// ---------------- fused prep: conv_x / conv_w / hist ----------------
__global__ __launch_bounds__(256) void prep(const float* __restrict__ x,
                                            bf16* __restrict__ xb,
                                            WPtrs wp, bf16* __restrict__ wb,
                                            const int* __restrict__ ei,
                                            int* __restrict__ deg) {
    const int gs = gridDim.x * 256;
    const int t0 = blockIdx.x * 256 + threadIdx.x;
    if (blockIdx.y == 0) {
        for (int i = t0; i < N_NODES * 128; i += gs)
            xb[i] = __float2bfloat16(x[i]);
    } else if (blockIdx.y == 1) {
        for (int i = t0; i < 49152; i += gs) {
            int y, o;
            if (i < 32768) { y = i >> 13; o = i & 8191; }
            else { y = 4 + ((i - 32768) >> 12); o = (i - 32768) & 4095; }
            wb[i] = __float2bfloat16(wp.p[y][o]);
        }
    } else {
        for (int e = t0; e < N_EDGES; e += gs)
            atomicAdd(&deg[ei[N_EDGES + e]], 1);
    }
}

// ---------------- MFMA GEMM body (64-row tile, 4 weight mats) ----------------
template <int K>
__device__ __forceinline__ void gemm_body(
    int blk, int tid,
    const bf16* __restrict__ A, const bf16* __restrict__ wb,
    const float* __restrict__ bq, const float* __restrict__ bk,
    const float* __restrict__ bv, const float* __restrict__ bs,
    bf16* __restrict__ qb, bf16* __restrict__ kvb, float* __restrict__ s) {
    const int wave = tid >> 6;
    const int lane = tid & 63;
    const int row0 = blk * 64;
    const int m  = lane & 15;
    const int kg = lane >> 4;
    const bf16* W = wb + (size_t)wave * 64 * K;

    f32x4 acc[4][4];
#pragma unroll
    for (int i = 0; i < 4; ++i)
#pragma unroll
        for (int j = 0; j < 4; ++j) acc[i][j] = (f32x4){0.f, 0.f, 0.f, 0.f};

#pragma unroll
    for (int k0 = 0; k0 < K; k0 += 32) {
        bf16x8 a[4], b[4];
#pragma unroll
        for (int i = 0; i < 4; ++i)
            a[i] = *(const bf16x8*)(A + (size_t)(row0 + i * 16 + m) * K + k0 + kg * 8);
#pragma unroll
        for (int j = 0; j < 4; ++j)
            b[j] = *(const bf16x8*)(W + (size_t)(j * 16 + m) * K + k0 + kg * 8);
#pragma unroll
        for (int i = 0; i < 4; ++i)
#pragma unroll
            for (int j = 0; j < 4; ++j)
                acc[i][j] = __builtin_amdgcn_mfma_f32_16x16x32_bf16(a[i], b[j], acc[i][j], 0, 0, 0);
    }

    const int crow = (lane >> 4) * 4;
    const int ccol = lane & 15;
    const float* B = (wave == 0) ? bq : (wave == 1) ? bk : (wave == 2) ? bv : bs;
    float bias[4];
#pragma unroll
    for (int j = 0; j < 4; ++j) bias[j] = B[j * 16 + ccol];

#pragma unroll
    for (int i = 0; i < 4; ++i)
#pragma unroll
        for (int r = 0; r < 4; ++r) {
            int gr = row0 + i * 16 + crow + r;
            if (gr >= N_NODES) continue;
#pragma unroll
            for (int j = 0; j < 4; ++j) {
                float val = acc[i][j][r] + bias[j];
                size_t idx = (size_t)gr * 64 + j * 16 + ccol;
                if (wave == 0) qb[idx] = __float2bfloat16(val);
                else if (wave == 1) kvb[idx * 2] = __float2bfloat16(val);
                else if (wave == 2) kvb[idx * 2 + 1] = __float2bfloat16(val);
                else s[idx] = val;
            }
        }
}

// layer-1 GEMM + scatter fused (independent work in one dispatch)
__global__ __launch_bounds__(256) void gemm1_scatter(
    const bf16* __restrict__ A, const bf16* __restrict__ wb,
    const float* __restrict__ bq, const float* __restrict__ bk,
    const float* __restrict__ bv, const float* __restrict__ bs,
    bf16* __restrict__ qb, bf16* __restrict__ kvb, float* __restrict__ s,
    const int* __restrict__ ei, int* __restrict__ cursor,
    int* __restrict__ csr_src) {
    if (blockIdx.x < GEMM_BLKS) {
        gemm_body<128>(blockIdx.x, threadIdx.x, A, wb, bq, bk, bv, bs, qb, kvb, s);
    } else {
        int e = (blockIdx.x - GEMM_BLKS) * 256 + threadIdx.x;
        if (e < N_EDGES) {
            int pos = atomicAdd(&cursor[ei[N_EDGES + e]], 1);
            csr_src[pos] = ei[e];
        }
    }
}

__global__ __launch_bounds__(256) void gemm2(
    const bf16* __restrict__ A, const bf16* __restrict__ wb,
    const float* __restrict__ bq, const float* __restrict__ bk,
    const float* __restrict__ bv, const float* __restrict__ bs,
    bf16* __restrict__ qb, bf16* __restrict__ kvb, float* __restrict__ s) {
    gemm_body<64>(blockIdx.x, threadIdx.x, A, wb, bq, bk, bv, bs, qb, kvb, s);
}

// ---------------- CSR scan ----------------
__global__ __launch_bounds__(256) void scan1(const int* __restrict__ deg,
                                             int* __restrict__ off,
                                             int* __restrict__ bsum) {
    __shared__ int sm[256];
    int i = blockIdx.x * 256 + threadIdx.x;
    int v = (i < N_NODES) ? deg[i] : 0;
    sm[threadIdx.x] = v;
    __syncthreads();
    for (int st = 1; st < 256; st <<= 1) {
        int t = (threadIdx.x >= (unsigned)st) ? sm[threadIdx.x - st] : 0;
        __syncthreads();
        sm[threadIdx.x] += t;
        __syncthreads();
    }
    if (i < N_NODES) off[i] = sm[threadIdx.x] - v;
    if (threadIdx.x == 255) bsum[blockIdx.x] = sm[255];
}

__global__ __launch_bounds__(256) void scan2(const int* __restrict__ bsum,
                                             int* __restrict__ boff) {
    __shared__ int sm[256];
    int b = threadIdx.x;
    int v = (b < NB_SCAN) ? bsum[b] : 0;
    sm[b] = v;
    __syncthreads();
    for (int st = 1; st < 256; st <<= 1) {
        int t = (b >= st) ? sm[b - st] : 0;
        __syncthreads();
        sm[b] += t;
        __syncthreads();
    }
    if (b < NB_SCAN) boff[b] = sm[b] - v;
    if (b == 255) boff[NB_SCAN] = sm[255];
}

__global__ __launch_bounds__(256) void scan3(int* __restrict__ off,
                                             const int* __restrict__ boff,
                                             int* __restrict__ cursor) {
    int i = blockIdx.x * 256 + threadIdx.x;
    if (i < N_NODES) {
        int v = off[i] + boff[blockIdx.x];
        off[i] = v;
        cursor[i] = v;
    }
    if (i == 0) off[N_NODES] = boff[NB_SCAN];
}

// ------------- Aggregation: wave/node, nt streaming, unroll 16 -------------
template <int H, bool RELU, typename OT>  // D = 64/H
__global__ __launch_bounds__(256) void agg_csr(const int* __restrict__ off,
                                               const int* __restrict__ csr_src,
                                               const bf16* __restrict__ qb,
                                               const unsigned int* __restrict__ kvu,
                                               const float* __restrict__ s,
                                               OT* __restrict__ out) {
    const int D = 64 / H;
    const float scale = (D == 16) ? 0.25f : 0.125f;
    const int lane = threadIdx.x & 63;
    const int n = (blockIdx.x * 256 + threadIdx.x) >> 6;
    if (n >= N_NODES) return;

    // q read once -> non-temporal (don't evict kv rows from L2)
    const float qv = b2f(__builtin_nontemporal_load(
        (const unsigned short*)qb + (size_t)n * 64 + lane));
    float acc = 0.f, dsum = 0.f;
    int j = off[n];
    const int j1 = off[n + 1];

    for (; j + 15 < j1; j += 16) {
        unsigned int w[16];
#pragma unroll
        for (int u = 0; u < 16; ++u)
            w[u] = kvu[(size_t)csr_src[j + u] * 64 + lane];
        float p[16];
#pragma unroll
        for (int u = 0; u < 16; ++u) p[u] = qv * b2f((unsigned short)w[u]);
#pragma unroll
        for (int o = 1; o < D; o <<= 1)
#pragma unroll
            for (int u = 0; u < 16; ++u) p[u] += __shfl_xor(p[u], o, 64);
#pragma unroll
        for (int u = 0; u < 16; ++u) {
            float e = __expf(p[u] * scale);
            acc += e * b2f((unsigned short)(w[u] >> 16));
            dsum += e;
        }
    }
    for (; j + 3 < j1; j += 4) {
        unsigned int w[4];
#pragma unroll
        for (int u = 0; u < 4; ++u)
            w[u] = kvu[(size_t)csr_src[j + u] * 64 + lane];
        float p[4];
#pragma unroll
        for (int u = 0; u < 4; ++u) p[u] = qv * b2f((unsigned short)w[u]);
#pragma unroll
        for (int o = 1; o < D; o <<= 1)
#pragma unroll
            for (int u = 0; u < 4; ++u) p[u] += __shfl_xor(p[u], o, 64);
#pragma unroll
        for (int u = 0; u < 4; ++u) {
            float e = __expf(p[u] * scale);
            acc += e * b2f((unsigned short)(w[u] >> 16));
            dsum += e;
        }
    }
    for (; j < j1; ++j) {
        unsigned int w = kvu[(size_t)csr_src[j] * 64 + lane];
        float p = qv * b2f((unsigned short)w);
#pragma unroll
        for (int o = 1; o < D; o <<= 1) p += __shfl_xor(p, o, 64);
        float e = __expf(p * scale);
        acc += e * b2f((unsigned short)(w >> 16));
        dsum += e;
    }
    float a = (dsum != 0.f) ? acc / dsum : 0.f;
    float sk = __builtin_nontemporal_load(s + (size_t)n * 64 + lane);
    float val = a + sk;
    if (RELU) val = fmaxf(val, 0.f);
    if constexpr (__hip_internal::is_same<OT, bf16>::value)
        out[(size_t)n * 64 + lane] = __float2bfloat16(val);  // hb: re-read by gemm2, keep cached
    else
        __builtin_nontemporal_store(val, out + (size_t)n * 64 + lane);  // d_out: nt
}

extern "C" void kernel_launch(void* const* d_in, const int* in_sizes, int n_in,
                              void* d_out, int out_size, void* d_ws, size_t ws_size,
                              hipStream_t stream) {
    const float* x  = (const float*)d_in[0];
    const int*   ei = (const int*)d_in[1];
    const float* bq1 = (const float*)d_in[3];
    const float* bk1 = (const float*)d_in[5];
    const float* bv1 = (const float*)d_in[7];
    const float* bs1 = (const float*)d_in[9];
    const float* bq2 = (const float*)d_in[11];
    const float* bk2 = (const float*)d_in[13];
    const float* bv2 = (const float*)d_in[15];
    const float* bs2 = (const float*)d_in[17];

    WPtrs wp;
    wp.p[0] = (const float*)d_in[2];
    wp.p[1] = (const float*)d_in[4];
    wp.p[2] = (const float*)d_in[6];
    wp.p[3] = (const float*)d_in[8];
    wp.p[4] = (const float*)d_in[10];
    wp.p[5] = (const float*)d_in[12];
    wp.p[6] = (const float*)d_in[14];
    wp.p[7] = (const float*)d_in[16];

    const size_t N = N_NODES;
    bf16* xb  = (bf16*)d_ws;                 // NPAD*128
    bf16* hb  = xb + (size_t)NPAD * 128;     // NPAD*64
    bf16* qb  = hb + (size_t)NPAD * 64;      // N*64
    bf16* kvb = qb + N * 64;                 // 2*N*64 interleaved
    bf16* wb  = kvb + 2 * N * 64;            // 49152
    float* s  = (float*)(wb + 49152);        // N*64
    int* deg  = (int*)(s + N * 64);          // N
    int* off  = deg + N_NODES;               // N+1
    int* cur  = off + N_NODES + 1;           // N
    int* bsum = cur + N_NODES;               // NB_SCAN
    int* boff = bsum + NB_SCAN;              // NB_SCAN+1
    int* csr  = boff + NB_SCAN + 1;          // E

    const int aggGrid = (N_NODES * 64 + 255) / 256;

    // ---------------- prep + CSR ----------------
    hipMemsetAsync(deg, 0, N_NODES * sizeof(int), stream);
    prep<<<dim3(1024, 3), 256, 0, stream>>>(x, xb, wp, wb, ei, deg);
    scan1<<<NB_SCAN, 256, 0, stream>>>(deg, off, bsum);
    scan2<<<1, 256, 0, stream>>>(bsum, boff);
    scan3<<<NB_SCAN, 256, 0, stream>>>(off, boff, cur);

    // ---------------- Layer 1 (gemm + scatter fused) ----------------
    gemm1_scatter<<<GEMM_BLKS + SCAT_BLKS, 256, 0, stream>>>(
        xb, wb, bq1, bk1, bv1, bs1, qb, kvb, s, ei, cur, csr);
    agg_csr<4, true, bf16><<<aggGrid, 256, 0, stream>>>(off, csr, qb,
                                                        (const unsigned int*)kvb, s, hb);

    // ---------------- Layer 2 ----------------
    gemm2<<<GEMM_BLKS, 256, 0, stream>>>(hb, wb + 32768, bq2, bk2, bv2, bs2,
                                         qb, kvb, s);
    agg_csr<1, false, float><<<aggGrid, 256, 0, stream>>>(off, csr, qb,
                                                          (const unsigned int*)kvb, s,
                                                          (float*)d_out);
}